// Round 4
// baseline (170.095 us; speedup 1.0000x reference)
//
#include <hip/hip_runtime.h>

// Problem constants (fixed by setup_inputs: 4096x4096 fp32).
#define H 4096
#define W 4096
#define TILE 64              // block output tile; 4 waves x (32x32) private quarters
#define QT 32                // per-wave quarter tile
#define QROWS 46             // padded rows: 32 + 2*7 (NO guard row needed: row-prefix only)
#define QSTRIDE 49           // guard col 0 + 46 data cols + 2 junk; odd stride
#define QARENA 2304          // 46*49 = 2254 -> padded to 36 chunks * 64 (junk tail in-arena)
#define NCH 36

// Async global->LDS: dest is wave-uniform base + lane*4 (linear), source per-lane.
#define GLOAD_LDS4(gp, lp) __builtin_amdgcn_global_load_lds(                 \
    (const __attribute__((address_space(1))) void*)(gp),                     \
    (__attribute__((address_space(3))) void*)(lp), 4, 0, 0)

// Pin a float into a VGPR at this program point. Non-volatile: the scheduler
// may still move it, but the value's def becomes an opaque asm result, so the
// backend CANNOT rematerialize it later by re-issuing the ds_read it came
// from. This is what forces the D-FIFO to live in registers (R2 post-mortem:
// without it the compiler kept VGPR=60 and re-read LDS, doubling epilogue
// LDS traffic).
#define PIN(v) asm("" : "+v"(v))

// Wave-autonomous, row-prefix-only design. Each wave owns a 32x32 output
// quarter with a private 46x49 LDS arena holding the ROW prefix sums R only.
// The column dimension is handled per-lane with running box sums and a
// 63-register FIFO of D_k values (D_k(a) = R(a,c1)-R(a,c0)), halving the
// epilogue's LDS reads (7 ds_read2/pixel vs 14) and deleting the column-scan
// phase. No __syncthreads anywhere; all hazards wave-internal.
__global__ __launch_bounds__(256, 4) void multi_box_kernel(
    const float* __restrict__ x,
    const float* __restrict__ base,
    float* __restrict__ out)
{
    __shared__ float Parena[4 * QARENA];   // 36.9 KB -> 4 blocks/CU, 16 indep waves

    const int tid  = threadIdx.x;
    const int lane = tid & 63;
    const int wv   = tid >> 6;
    float* __restrict__ Q = Parena + wv * QARENA;

    // This wave's output quarter origin.
    const int qx0 = blockIdx.x * TILE + (wv & 1) * QT;
    const int qy0 = blockIdx.y * TILE + (wv >> 1) * QT;

    // ---- Phase 1: stage padded 46x46 tile. Arena row a = padded-tile row a
    // (global gy = qy0 + a - 7), data cols at arena cols 1..46 (gx = qx0+col-8).
    // Guard col 0 / junk cols 47..48 / tail dwords get clamped garbage.
    #pragma unroll
    for (int ch = 0; ch < NCH; ++ch) {
        const int d   = ch * 64 + lane;
        const int row = d / 49;              // magic-mul
        const int col = d - row * 49;
        const int gy  = min(max(qy0 + row - 7, 0), H - 1);  // replicate padding
        const int gx  = min(max(qx0 + col - 8, 0), W - 1);
        GLOAD_LDS4(x + (size_t)gy * W + gx, Q + ch * 64);
    }
    asm volatile("s_waitcnt vmcnt(0)" ::: "memory");
    __builtin_amdgcn_sched_barrier(0);       // rule 18: pin following DS ops after wait

    // ---- Zero guard col 0 (rows 0..45) after the drain.
    if (lane < QROWS) Q[lane * QSTRIDE] = 0.0f;

    // ---- Phase 2: row prefix. Lane t scans row t (46 elems, cols 1..46),
    // batched 8-wide. Lane addr stride 49 -> bank stride 17 -> conflict-free.
    if (lane < QROWS) {
        float v = 0.0f;
        const int rb = lane * QSTRIDE + 1;
        #pragma unroll
        for (int j0 = 0; j0 < 40; j0 += 8) {
            float a0 = Q[rb+j0+0], a1 = Q[rb+j0+1], a2 = Q[rb+j0+2], a3 = Q[rb+j0+3];
            float a4 = Q[rb+j0+4], a5 = Q[rb+j0+5], a6 = Q[rb+j0+6], a7 = Q[rb+j0+7];
            float v0 = v  + a0, v1 = v0 + a1, v2 = v1 + a2, v3 = v2 + a3;
            float v4 = v3 + a4, v5 = v4 + a5, v6 = v5 + a6, v7 = v6 + a7;
            Q[rb+j0+0] = v0; Q[rb+j0+1] = v1; Q[rb+j0+2] = v2; Q[rb+j0+3] = v3;
            Q[rb+j0+4] = v4; Q[rb+j0+5] = v5; Q[rb+j0+6] = v6; Q[rb+j0+7] = v7;
            v = v7;
        }
        {   // tail 6 (j = 40..45)
            const int b = rb + 40;
            float a0 = Q[b+0], a1 = Q[b+1], a2 = Q[b+2], a3 = Q[b+3], a4 = Q[b+4], a5 = Q[b+5];
            float v0 = v  + a0, v1 = v0 + a1, v2 = v1 + a2;
            float v3 = v2 + a3, v4 = v3 + a4, v5 = v4 + a5;
            Q[b+0] = v0; Q[b+1] = v1; Q[b+2] = v2; Q[b+3] = v3; Q[b+4] = v4; Q[b+5] = v5;
        }
    }

    // ---- Epilogue: lane (pc, hh) owns column pc, rows hh*16..hh*16+15.
    // For pixel row ry, kernel radius r: window = arena rows [ry+7-r, ry+7+r],
    // cols (c0,c1) = (pc+7-r, pc+8+r). D_k(a) = Q[a*49+c1] - Q[a*49+c0]
    // (one ds_read2). box_k slides down the column: += D(new) - D(old<ring>).
    const int pc  = lane & 31;
    const int hh  = lane >> 5;
    const int y0  = hh * 16;
    const int gx  = qx0 + pc;
    const int gy0 = qy0 + y0;

    float box[7] = {0.f, 0.f, 0.f, 0.f, 0.f, 0.f, 0.f};
    float ring[63];   // per-k FIFO, base RB(kk)=kk*kk+2*kk, depth 2kk+3; all
                      // indices compile-time under full unroll; PIN() forces
                      // each element to stay VGPR-resident (no LDS re-read)

    // ---- Init: rows o = 0..14 feed the r >= |o-7| rings; 63 ds_read2 total.
    #pragma unroll
    for (int g = 0; g < 3; ++g) {
        int gb = (y0 + g * 5) * QSTRIDE + pc;
        asm volatile("" : "+v"(gb));         // opaque base: offsets <= 211 dwords
        #pragma unroll
        for (int oo = 0; oo < 5; ++oo) {
            const int o = g * 5 + oo;
            #pragma unroll
            for (int kk = 0; kk < 7; ++kk) {
                const int r = kk + 1;
                if (o < 7 - r || o > 7 + r) continue;   // compile-time pruned
                float lo = Q[gb + oo * QSTRIDE + (7 - r)];
                float hi = Q[gb + oo * QSTRIDE + (8 + r)];
                float D  = hi - lo;
                box[kk] += D;
                PIN(D);                                  // register-resident FIFO
                ring[kk * kk + 2 * kk + (o - (7 - r))] = D;
            }
        }
    }

    // Prefetch base[] now (after init's register peak) -> overlaps the step loop.
    float bv[16];
    {
        const float* bp = base + (size_t)gy0 * W + gx;
        #pragma unroll
        for (int yy = 0; yy < 16; ++yy) bv[yy] = bp[(size_t)yy * W];
    }

    // ---- Pixel yy = 0 straight from the init boxes.
    {
        float acc = 0.f;
        #pragma unroll
        for (int kk = 0; kk < 7; ++kk) {
            const int k = 2 * kk + 3;
            acc = fmaf(box[kk], 1.0f / (7.0f * (float)(k * k)), acc);
        }
        out[(size_t)gy0 * W + gx] = acc * bv[0];
    }

    // ---- Steps yy = 1..15: per k one new D (ds_read2), old D from the ring.
    #pragma unroll
    for (int yy = 1; yy < 16; ++yy) {
        int nb1 = (y0 + yy + 8)  * QSTRIDE + pc;   // rows for r=1..5 (+0..4 rows)
        int nb2 = (y0 + yy + 13) * QSTRIDE + pc;   // rows for r=6,7  (+0..1 rows)
        asm volatile("" : "+v"(nb1), "+v"(nb2));   // max offsets 209 / 64 dwords
        float acc = 0.f;
        #pragma unroll
        for (int kk = 0; kk < 7; ++kk) {
            const int r = kk + 1;
            float lo, hi;
            if (r <= 5) {
                lo = Q[nb1 + (r - 1) * QSTRIDE + (7 - r)];
                hi = Q[nb1 + (r - 1) * QSTRIDE + (8 + r)];
            } else {
                lo = Q[nb2 + (r - 6) * QSTRIDE + (7 - r)];
                hi = Q[nb2 + (r - 6) * QSTRIDE + (8 + r)];
            }
            float D = hi - lo;
            const int slot = (yy - 1) % (2 * r + 1);   // compile-time
            const int ri   = kk * kk + 2 * kk + slot;
            box[kk] += D - ring[ri];
            PIN(D);                                    // register-resident FIFO
            ring[ri] = D;
            const int k = 2 * r + 1;
            acc = fmaf(box[kk], 1.0f / (7.0f * (float)(k * k)), acc);
        }
        out[(size_t)(gy0 + yy) * W + gx] = acc * bv[yy];
    }
}

extern "C" void kernel_launch(void* const* d_in, const int* in_sizes, int n_in,
                              void* d_out, int out_size, void* d_ws, size_t ws_size,
                              hipStream_t stream) {
    const float* x    = (const float*)d_in[0];
    const float* base = (const float*)d_in[1];
    float* out        = (float*)d_out;

    dim3 grid(W / TILE, H / TILE);  // 64 x 64 blocks, 4 autonomous waves each
    multi_box_kernel<<<grid, 256, 0, stream>>>(x, base, out);
}